// Round 11
// baseline (384.443 us; speedup 1.0000x reference)
//
#include <hip/hip_runtime.h>

// GCN link-prediction pipeline, algebraically reduced twice via linearity:
//   xw1 = x @ W1                                   [N,64] dense
//   y1  = relu(segsum_dst(w*xw1[src])) @ [MA|MB]   [N,4]  (proj fused in epilogue)
//           where MA = W2@Wdec[:, :64]^T, MB = W2@Wdec[:, 64:]^T  (64x2 each)
//   z2  = segsum_dst(w*y1[src])                    [N,4]  (16B/edge gathers!)
//   out[e] = z2[ps[e]][0:2] + z2[pd[e]][2:4]
// CSR-by-dst built once per call (reused by both aggregation passes) to avoid
// per-edge float atomics. r10: fix compile error — nontemporal store of float2
// (HIP_vector_type) rejected; bit-cast through unsigned long long instead.

// 2 edges/thread, int2 dst read: halves wave count of the atomic-bound pass.
__global__ __launch_bounds__(256) void k_hist(const int* __restrict__ ei, int E,
                                              int* __restrict__ counts) {
  int e = (blockIdx.x * 256 + threadIdx.x) * 2;
  if (e + 1 < E) {
    int2 d = *(const int2*)(ei + E + e);
    atomicAdd(&counts[d.x], 1);
    atomicAdd(&counts[d.y], 1);
  } else if (e < E) {
    atomicAdd(&counts[ei[E + e]], 1);
  }
}

// Block 0: single-block scan (counts in 'cnt' -> cursor start offsets, offs[N+1]).
// Block 1: Mab[k*4+{0,1,2,3}] = { MA[k][0], MA[k][1], MB[k][0], MB[k][1] }.
__global__ __launch_bounds__(1024) void k_scan_mab(int* __restrict__ cnt,
                                                   int* __restrict__ offs, int N,
                                                   const float* __restrict__ W2,
                                                   const float* __restrict__ Wd,
                                                   float* __restrict__ Mab) {
  if (blockIdx.x == 1) {           // tiny projection-matrix build
    int t = threadIdx.x;
    if (t < 256) {
      int k = t >> 2, idx = t & 3;
      int c = idx & 1, half = idx >> 1;
      const float* w2row = W2 + k * 64;
      const float* wdrow = Wd + c * 128 + half * 64;
      float s = 0.f;
#pragma unroll 8
      for (int j = 0; j < 64; ++j) s = fmaf(w2row[j], wdrow[j], s);
      Mab[t] = s;
    }
    return;
  }
  __shared__ int sums[1024];
  int t = threadIdx.x;
  int CH = (((N + 1023) >> 10) + 3) & ~3;   // per-thread chunk, multiple of 4
  int lo = t * CH, hi = min(lo + CH, N);
  if (lo > N) lo = N;
  int s = 0;
  int i = lo;
  for (; i + 4 <= hi; i += 4) {
    int4 v = *(const int4*)(cnt + i);
    s += v.x + v.y + v.z + v.w;
  }
  for (; i < hi; ++i) s += cnt[i];
  sums[t] = s;
  __syncthreads();
  for (int off = 1; off < 1024; off <<= 1) {
    int v = (t >= off) ? sums[t - off] : 0;
    __syncthreads();
    sums[t] += v;
    __syncthreads();
  }
  int run = (t == 0) ? 0 : sums[t - 1];
  i = lo;
  for (; i + 4 <= hi; i += 4) {
    int4 v = *(const int4*)(cnt + i);
    int4 o;
    o.x = run; run += v.x;
    o.y = run; run += v.y;
    o.z = run; run += v.z;
    o.w = run; run += v.w;
    *(int4*)(offs + i) = o;
    *(int4*)(cnt + i) = o;   // cursor initialized to start offsets
  }
  for (; i < hi; ++i) {
    int c = cnt[i];
    offs[i] = run; cnt[i] = run; run += c;
  }
  if (hi == N) offs[N] = run;  // == E (all covering threads write the same total)
}

// 2 edges/thread: int2 src + int2 dst + float2 w (3 vector loads vs 6 scalar).
__global__ __launch_bounds__(256) void k_fill(const int* __restrict__ ei,
                                              const float* __restrict__ ew, int E,
                                              int* __restrict__ cursor,
                                              int2* __restrict__ perm) {
  int e = (blockIdx.x * 256 + threadIdx.x) * 2;
  if (e + 1 < E) {
    int2 sv = *(const int2*)(ei + e);
    int2 dv = *(const int2*)(ei + E + e);
    float2 wv = *(const float2*)(ew + e);
    int p0 = atomicAdd(&cursor[dv.x], 1);
    perm[p0] = make_int2(sv.x, __float_as_int(wv.x));
    int p1 = atomicAdd(&cursor[dv.y], 1);
    perm[p1] = make_int2(sv.y, __float_as_int(wv.y));
  } else if (e < E) {
    int dst = ei[E + e];
    int pos = atomicAdd(&cursor[dst], 1);
    perm[pos] = make_int2(ei[e], __float_as_int(ew[e]));
  }
}

// Y[n][64] = X[n][128] @ W[128][64].
// Block tile 64x64; 4 waves, wave w -> cols w*16..+15. Lane grid 16x4:
// rg = lane>>2 (rows rg*4..+3), cg = lane&3 (cols w*16+cg*4..+3); 4x4 acc/lane.
// Per 4-k: 8 ds_read_b128 feed 64 FMA instrs -> VALU-bound under both LDS cost
// models (instr ~12cy: 96 < 128; byte 112B/cy: 73 < 128). Stride 132 padding:
// X rows staggered 4 banks apart; W cols read by 4-lane broadcast groups.
__global__ __launch_bounds__(256) void k_gemm128(const float* __restrict__ X,
                                                 const float* __restrict__ W,
                                                 float* __restrict__ Y, int n) {
  constexpr int K = 128;
  constexpr int RPB = 64;
  constexpr int LDT = K + 4;            // 132-float padded stride
  __shared__ float Xs[RPB * LDT];       // [row][k]  33 KB
  __shared__ float WsT[64 * LDT];       // [col][k]  33 KB
  int t = threadIdx.x;
  for (int i = t; i < 2048; i += 256) { // W is [128][64] row-major = 2048 float4
    float4 v = ((const float4*)W)[i];
    int k = i >> 4;                     // W row (k index)
    int c = (i & 15) << 2;              // W col base
    WsT[(c + 0) * LDT + k] = v.x;
    WsT[(c + 1) * LDT + k] = v.y;
    WsT[(c + 2) * LDT + k] = v.z;
    WsT[(c + 3) * LDT + k] = v.w;
  }
  int r0 = blockIdx.x * RPB;
  int rows = min(RPB, n - r0);
  const float4* Xg = (const float4*)(X + (size_t)r0 * K);
  for (int i = t; i < rows * 32; i += 256) {
    float4 v = Xg[i];
    int r = i >> 5, c = (i & 31) << 2;  // 132 = 4*33 -> float4-aligned dest
    *(float4*)(&Xs[r * LDT + c]) = v;
  }
  __syncthreads();
  int w = t >> 6, lane = t & 63;
  int rg = lane >> 2, cg = lane & 3;
  const float* xb = &Xs[(rg * 4) * LDT];
  const float* wb = &WsT[(w * 16 + cg * 4) * LDT];
  float acc[4][4] = {};
  for (int k = 0; k < K; k += 4) {
    float4 xv[4], wv[4];
#pragma unroll
    for (int i = 0; i < 4; ++i) xv[i] = *(const float4*)(xb + i * LDT + k);
#pragma unroll
    for (int j = 0; j < 4; ++j) wv[j] = *(const float4*)(wb + j * LDT + k);
#pragma unroll
    for (int i = 0; i < 4; ++i)
#pragma unroll
      for (int j = 0; j < 4; ++j) {
        acc[i][j] = fmaf(xv[i].x, wv[j].x, acc[i][j]);
        acc[i][j] = fmaf(xv[i].y, wv[j].y, acc[i][j]);
        acc[i][j] = fmaf(xv[i].z, wv[j].z, acc[i][j]);
        acc[i][j] = fmaf(xv[i].w, wv[j].w, acc[i][j]);
      }
  }
  // tail rows compute on unwritten LDS but are discarded by the r<n guard
#pragma unroll
  for (int i = 0; i < 4; ++i) {
    int r = r0 + rg * 4 + i;
    if (r < n) {
      float4 o = make_float4(acc[i][0], acc[i][1], acc[i][2], acc[i][3]);
      *(float4*)(&Y[(size_t)r * 64 + w * 16 + cg * 4]) = o;
    }
  }
}

__device__ __forceinline__ void nt_edge(const int2* p, int& src, float& w) {
  unsigned long long u =
      __builtin_nontemporal_load((const unsigned long long*)p);
  src = (int)(unsigned)(u & 0xffffffffull);
  w = __int_as_float((int)(unsigned)(u >> 32));
}

// Layer 1 + fused projection: wave per node.
// acc[lane] = relu(sum_e w*Xf[src][lane]);  y1[node][c] = sum_lane acc*Mab[lane*4+c]
// 8-deep gather pipeline: 8 independent perm-loads + 8 row-gathers in flight.
__global__ __launch_bounds__(256) void k_agg1(const int* __restrict__ offs,
                                              const int2* __restrict__ perm,
                                              const float* __restrict__ Xf,
                                              const float* __restrict__ Mab,
                                              float4* __restrict__ y1, int n) {
  int node = (blockIdx.x * 256 + threadIdx.x) >> 6;
  int lane = threadIdx.x & 63;
  if (node >= n) return;
  float4 m = ((const float4*)Mab)[lane];   // hoisted: hides under gathers
  int p0 = offs[node], p1 = offs[node + 1];
  float acc = 0.f;
  int p = p0;
  for (; p + 8 <= p1; p += 8) {
    int s[8]; float w[8], v[8];
#pragma unroll
    for (int j = 0; j < 8; ++j) nt_edge(perm + p + j, s[j], w[j]);
#pragma unroll
    for (int j = 0; j < 8; ++j) v[j] = Xf[(size_t)s[j] * 64 + lane];
#pragma unroll
    for (int j = 0; j < 8; ++j) acc = fmaf(w[j], v[j], acc);
  }
  for (; p + 2 <= p1; p += 2) {
    int s0, s1; float w0, w1;
    nt_edge(perm + p, s0, w0);
    nt_edge(perm + p + 1, s1, w1);
    float v0 = Xf[(size_t)s0 * 64 + lane];
    float v1 = Xf[(size_t)s1 * 64 + lane];
    acc = fmaf(w0, v0, acc);
    acc = fmaf(w1, v1, acc);
  }
  if (p < p1) {
    int s0; float w0;
    nt_edge(perm + p, s0, w0);
    acc = fmaf(w0, Xf[(size_t)s0 * 64 + lane], acc);
  }
  acc = fmaxf(acc, 0.f);                   // relu(z1[node][lane])
  float ya0 = acc * m.x, ya1 = acc * m.y;
  float yb0 = acc * m.z, yb1 = acc * m.w;
#pragma unroll
  for (int off = 32; off > 0; off >>= 1) {
    ya0 += __shfl_xor(ya0, off, 64);
    ya1 += __shfl_xor(ya1, off, 64);
    yb0 += __shfl_xor(yb0, off, 64);
    yb1 += __shfl_xor(yb1, off, 64);
  }
  if (lane == 0) y1[node] = make_float4(ya0, ya1, yb0, yb1);
}

// Layer 2 on projected features: wave per node, 16 edge-slots x 4 features.
// z2[node][c] = sum_e w[e] * y1[src[e]][c]   (y1 is 1.6 MB -> L2-resident)
__global__ __launch_bounds__(256) void k_agg2(const int* __restrict__ offs,
                                              const int2* __restrict__ perm,
                                              const float* __restrict__ y1,
                                              float* __restrict__ z2, int n) {
  int node = (blockIdx.x * 256 + threadIdx.x) >> 6;
  int lane = threadIdx.x & 63;
  if (node >= n) return;
  int p0 = offs[node], p1 = offs[node + 1];
  int slot = lane >> 2, c = lane & 3;
  float acc = 0.f;
  for (int p = p0 + slot; p < p1; p += 16) {
    int s; float w;
    nt_edge(perm + p, s, w);               // 4 lanes share each entry
    acc = fmaf(w, y1[(size_t)s * 4 + c], acc);
  }
  acc += __shfl_xor(acc, 4, 64);           // reduce over slot bits 2..5
  acc += __shfl_xor(acc, 8, 64);
  acc += __shfl_xor(acc, 16, 64);
  acc += __shfl_xor(acc, 32, 64);
  if (lane < 4) z2[(size_t)node * 4 + c] = acc;
}

// out[e][c] = z2[s][c] + z2[d][2+c]
__global__ __launch_bounds__(256) void k_decode(const int* __restrict__ pei,
                                                const float4* __restrict__ z2,
                                                float2* __restrict__ out, int PE) {
  int e = blockIdx.x * 256 + threadIdx.x;
  if (e >= PE) return;
  int s = __builtin_nontemporal_load(pei + e);
  int d = __builtin_nontemporal_load(pei + PE + e);
  float4 a = z2[s];                         // use .x .y
  float4 b = z2[d];                         // use .z .w
  float2 o = make_float2(a.x + b.z, a.y + b.w);
  // nontemporal builtin rejects HIP_vector_type; bit-cast 8B through u64
  unsigned long long obits;
  __builtin_memcpy(&obits, &o, 8);
  __builtin_nontemporal_store(obits, (unsigned long long*)(out + e));
}

extern "C" void kernel_launch(void* const* d_in, const int* in_sizes, int n_in,
                              void* d_out, int out_size, void* d_ws, size_t ws_size,
                              hipStream_t stream) {
  const float* x   = (const float*)d_in[0];
  const int*   ei  = (const int*)d_in[1];
  const float* ew  = (const float*)d_in[2];
  const int*   pei = (const int*)d_in[3];
  const float* W1  = (const float*)d_in[4];
  const float* W2  = (const float*)d_in[5];
  const float* Wd  = (const float*)d_in[6];
  float* out = (float*)d_out;

  const int N  = in_sizes[0] / 128;
  const int E  = in_sizes[1] / 2;
  const int PE = in_sizes[3] / 2;

  char* ws = (char*)d_ws;
  auto align256 = [](size_t v) { return (v + 255) & ~(size_t)255; };
  size_t off = 0;
  float*  bufA = (float*)(ws + off);  off = align256(off + (size_t)N * 64 * 4);  // xw1
  int*    offs = (int*)(ws + off);    off = align256(off + (size_t)(N + 1) * 4);
  int*    curs = (int*)(ws + off);    off = align256(off + (size_t)N * 4);
  int2*   perm = (int2*)(ws + off);   off = align256(off + (size_t)E * 8);
  float4* y1   = (float4*)(ws + off); off = align256(off + (size_t)N * 16);
  float*  z2   = (float*)(ws + off);  off = align256(off + (size_t)N * 16);
  float*  Mab  = (float*)(ws + off);  off = align256(off + 256 * 4);
  (void)ws_size; (void)n_in; (void)out_size;

  const int Epairs = (E + 1) / 2;
  (void)hipMemsetAsync(curs, 0, (size_t)N * 4, stream);
  k_hist<<<(Epairs + 255) / 256, 256, 0, stream>>>(ei, E, curs);
  k_scan_mab<<<2, 1024, 0, stream>>>(curs, offs, N, W2, Wd, Mab);
  k_fill<<<(Epairs + 255) / 256, 256, 0, stream>>>(ei, ew, E, curs, perm);

  k_gemm128<<<(N + 63) / 64, 256, 0, stream>>>(x, W1, bufA, N);                 // xw1
  k_agg1<<<(N + 3) / 4, 256, 0, stream>>>(offs, perm, bufA, Mab, y1, N);        // y1
  k_agg2<<<(N + 3) / 4, 256, 0, stream>>>(offs, perm, (const float*)y1, z2, N); // z2
  k_decode<<<(PE + 255) / 256, 256, 0, stream>>>(pei, (const float4*)z2,
                                                 (float2*)out, PE);
}